// Round 2
// baseline (1261.009 us; speedup 1.0000x reference)
//
#include <hip/hip_runtime.h>

#define B_SZ 2048
#define HID  1024
#define G4   4096
#define IN_D 512
#define T_LEN 20

#define BM 128
#define BN 32
#define BK 64
#define LDK 72   // padded LDS k-stride in shorts: 144B = +4 banks/row -> conflict-free

typedef __attribute__((ext_vector_type(8))) short bf16x8;
typedef __attribute__((ext_vector_type(4))) float f32x4;

__device__ __forceinline__ float bf2f(ushort u){
  union { unsigned int i; float f; } v; v.i = ((unsigned int)u) << 16; return v.f;
}
__device__ __forceinline__ ushort f2bf(float f){
  union { float f; unsigned int i; } v; v.f = f;
  unsigned int r = v.i + 0x7fffu + ((v.i >> 16) & 1u);
  return (ushort)(r >> 16);
}
__device__ __forceinline__ float rdv(const void* p, long idx, int fl){
  return fl ? ((const float*)p)[idx] : bf2f(((const ushort*)p)[idx]);
}
__device__ __forceinline__ float sigm(float x){ return 1.0f/(1.0f + __expf(-x)); }
__device__ __forceinline__ float tanh_f(float x){
  float e = __expf(2.0f*x);
  return 1.0f - 2.0f/(e + 1.0f);
}

// flag=1 -> inputs are fp32; flag=0 -> inputs are bf16.
// For LITTLE-ENDIAN fp32, the EVEN ushort positions are low mantissa halves ->
// reinterpreted as bf16 they have random exponents (~84% outside [1e-8,1e4]).
// (Round-1 bug: odd positions are fp32 HIGH halves == valid bf16 truncations.)
__global__ void detect_dtype(const ushort* __restrict__ h0bits, int* __restrict__ flag){
  int weird = 0;
  for (int i = 0; i < 256; i += 2){
    float a = fabsf(bf2f(h0bits[i]));
    if (!(a >= 1e-8f && a <= 1e4f)) weird++;
  }
  *flag = (weird >= 32) ? 1 : 0;
}

// Canonicalize state: h0 -> (hi,lo) bf16 pair, c0 -> fp32, W_hh -> (hi,lo) bf16 pair.
__global__ void canon(const void* __restrict__ h0, const void* __restrict__ c0,
                      const void* __restrict__ whh, const int* __restrict__ flag,
                      ushort* __restrict__ hAhi, ushort* __restrict__ hAlo,
                      float* __restrict__ c_state,
                      ushort* __restrict__ whi, ushort* __restrict__ wlo){
  const int fl = *flag;
  long i = (long)blockIdx.x * 256 + threadIdx.x;
  const long N1 = (long)B_SZ * HID;
  const long N3 = (long)G4 * HID;
  if (i < N1){
    float x = rdv(h0, i, fl);
    ushort hi = f2bf(x);
    hAhi[i] = hi; hAlo[i] = f2bf(x - bf2f(hi));
    return;
  }
  i -= N1;
  if (i < N1){ c_state[i] = rdv(c0, i, fl); return; }
  i -= N1;
  if (i < N3){
    float x = rdv(whh, i, fl);
    ushort hi = f2bf(x);
    whi[i] = hi; wlo[i] = f2bf(x - bf2f(hi));
  }
}

// Fold embedding + input GEMM + biases into rank-2 update (exact fp32):
// gates_x[t,b,n] = obs[t,b,0]*M0[n] + obs[t,b,1]*M1[n] + Beff[n]
__global__ void fold_emb(const void* __restrict__ Wih, const void* __restrict__ Wemb,
                         const void* __restrict__ bemb, const void* __restrict__ bih,
                         const void* __restrict__ bhh, const int* __restrict__ flag,
                         float* __restrict__ M0, float* __restrict__ M1, float* __restrict__ Beff){
  const int n = blockIdx.x;
  const int lane = threadIdx.x;
  const int fl = *flag;
  float s0 = 0.f, s1 = 0.f, sb = 0.f;
  for (int j = lane; j < IN_D; j += 64){
    float w  = rdv(Wih, (long)n*IN_D + j, fl);
    float e0 = rdv(Wemb, 2L*j, fl);
    float e1 = rdv(Wemb, 2L*j + 1, fl);
    float be = rdv(bemb, j, fl);
    s0 += w*e0; s1 += w*e1; sb += w*be;
  }
  #pragma unroll
  for (int off = 32; off > 0; off >>= 1){
    s0 += __shfl_down(s0, off, 64);
    s1 += __shfl_down(s1, off, 64);
    sb += __shfl_down(sb, off, 64);
  }
  if (lane == 0){
    M0[n] = s0; M1[n] = s1;
    Beff[n] = sb + rdv(bih, n, fl) + rdv(bhh, n, fl);
  }
}

// One LSTM step. gates = h@W_hh^T done in split precision:
// h = h_hi + h_lo, W = W_hi + W_lo; acc = h_hi*W_hi + h_lo*W_hi + h_hi*W_lo
// (dropped lo*lo term is ~2^-18 relative). c stays fp32 -> fp32-accurate recurrence.
__global__ __launch_bounds__(256, 2)
void lstm_step(const ushort* __restrict__ hin_hi, const ushort* __restrict__ hin_lo,
               ushort* __restrict__ hout_hi, ushort* __restrict__ hout_lo,
               void* __restrict__ out_final,
               float* __restrict__ c_state,
               const ushort* __restrict__ whi, const ushort* __restrict__ wlo,
               const float* __restrict__ M0, const float* __restrict__ M1,
               const float* __restrict__ Beff,
               const void* __restrict__ obs_raw, int t_step,
               const int* __restrict__ flag, int is_final)
{
  __shared__ ushort ldsAhi[BM * LDK];
  __shared__ ushort ldsAlo[BM * LDK];
  __shared__ ushort ldsBhi[4][BN * LDK];
  __shared__ ushort ldsBlo[4][BN * LDK];   // total 72 KB

  const int tid  = threadIdx.x;
  const int wave = tid >> 6;
  const int lane = tid & 63;
  const int l15  = lane & 15;
  const int quad = lane >> 4;
  const int bm_0 = blockIdx.x * BM;
  const int n0   = blockIdx.y * BN;

  f32x4 acc[4][2][2];
  #pragma unroll
  for (int g = 0; g < 4; g++)
    #pragma unroll
    for (int mt = 0; mt < 2; mt++)
      #pragma unroll
      for (int nt = 0; nt < 2; nt++)
        acc[g][mt][nt] = (f32x4){0.f, 0.f, 0.f, 0.f};

  const int c8   = (tid & 7) * 8;   // 16B slot
  const int rowA = tid >> 3;        // 0..31

  for (int k0 = 0; k0 < HID; k0 += BK) {
    __syncthreads();
    #pragma unroll
    for (int i = 0; i < 4; i++) {
      const int r = rowA + 32*i;
      const size_t go = (size_t)(bm_0 + r)*HID + k0 + c8;
      *reinterpret_cast<uint4*>(&ldsAhi[r*LDK + c8]) = *reinterpret_cast<const uint4*>(hin_hi + go);
      *reinterpret_cast<uint4*>(&ldsAlo[r*LDK + c8]) = *reinterpret_cast<const uint4*>(hin_lo + go);
    }
    #pragma unroll
    for (int g = 0; g < 4; g++) {
      const size_t go = (size_t)(g*HID + n0 + rowA)*HID + k0 + c8;
      *reinterpret_cast<uint4*>(&ldsBhi[g][rowA*LDK + c8]) = *reinterpret_cast<const uint4*>(whi + go);
      *reinterpret_cast<uint4*>(&ldsBlo[g][rowA*LDK + c8]) = *reinterpret_cast<const uint4*>(wlo + go);
    }
    __syncthreads();

    #pragma unroll
    for (int ks = 0; ks < 2; ks++) {
      const int kof = ks*32 + quad*8;
      bf16x8 ah0 = *reinterpret_cast<const bf16x8*>(&ldsAhi[(wave*32 +      l15)*LDK + kof]);
      bf16x8 ah1 = *reinterpret_cast<const bf16x8*>(&ldsAhi[(wave*32 + 16 + l15)*LDK + kof]);
      bf16x8 al0 = *reinterpret_cast<const bf16x8*>(&ldsAlo[(wave*32 +      l15)*LDK + kof]);
      bf16x8 al1 = *reinterpret_cast<const bf16x8*>(&ldsAlo[(wave*32 + 16 + l15)*LDK + kof]);
      #pragma unroll
      for (int g = 0; g < 4; g++) {
        bf16x8 bh0 = *reinterpret_cast<const bf16x8*>(&ldsBhi[g][(     l15)*LDK + kof]);
        bf16x8 bh1 = *reinterpret_cast<const bf16x8*>(&ldsBhi[g][(16 + l15)*LDK + kof]);
        bf16x8 bl0 = *reinterpret_cast<const bf16x8*>(&ldsBlo[g][(     l15)*LDK + kof]);
        bf16x8 bl1 = *reinterpret_cast<const bf16x8*>(&ldsBlo[g][(16 + l15)*LDK + kof]);

        acc[g][0][0] = __builtin_amdgcn_mfma_f32_16x16x32_bf16(ah0, bh0, acc[g][0][0], 0, 0, 0);
        acc[g][1][0] = __builtin_amdgcn_mfma_f32_16x16x32_bf16(ah1, bh0, acc[g][1][0], 0, 0, 0);
        acc[g][0][1] = __builtin_amdgcn_mfma_f32_16x16x32_bf16(ah0, bh1, acc[g][0][1], 0, 0, 0);
        acc[g][1][1] = __builtin_amdgcn_mfma_f32_16x16x32_bf16(ah1, bh1, acc[g][1][1], 0, 0, 0);

        acc[g][0][0] = __builtin_amdgcn_mfma_f32_16x16x32_bf16(al0, bh0, acc[g][0][0], 0, 0, 0);
        acc[g][1][0] = __builtin_amdgcn_mfma_f32_16x16x32_bf16(al1, bh0, acc[g][1][0], 0, 0, 0);
        acc[g][0][1] = __builtin_amdgcn_mfma_f32_16x16x32_bf16(al0, bh1, acc[g][0][1], 0, 0, 0);
        acc[g][1][1] = __builtin_amdgcn_mfma_f32_16x16x32_bf16(al1, bh1, acc[g][1][1], 0, 0, 0);

        acc[g][0][0] = __builtin_amdgcn_mfma_f32_16x16x32_bf16(ah0, bl0, acc[g][0][0], 0, 0, 0);
        acc[g][1][0] = __builtin_amdgcn_mfma_f32_16x16x32_bf16(ah1, bl0, acc[g][1][0], 0, 0, 0);
        acc[g][0][1] = __builtin_amdgcn_mfma_f32_16x16x32_bf16(ah0, bl1, acc[g][0][1], 0, 0, 0);
        acc[g][1][1] = __builtin_amdgcn_mfma_f32_16x16x32_bf16(ah1, bl1, acc[g][1][1], 0, 0, 0);
      }
    }
  }

  // Epilogue: fused LSTM cell. C/D layout: col = lane&15, row = quad*4 + reg.
  const int fl = *flag;
  #pragma unroll
  for (int nt = 0; nt < 2; nt++) {
    const int j = n0 + nt*16 + l15;
    float bi[4], m0v[4], m1v[4];
    #pragma unroll
    for (int g = 0; g < 4; g++) {
      bi[g]  = Beff[g*HID + j];
      m0v[g] = M0[g*HID + j];
      m1v[g] = M1[g*HID + j];
    }
    #pragma unroll
    for (int mt = 0; mt < 2; mt++) {
      #pragma unroll
      for (int r = 0; r < 4; r++) {
        const int b = bm_0 + wave*32 + mt*16 + quad*4 + r;
        const long oidx = ((long)t_step * B_SZ + b) * 2;
        const float o0 = rdv(obs_raw, oidx, fl);
        const float o1 = rdv(obs_raw, oidx + 1, fl);
        const size_t off = (size_t)b*HID + j;
        float pi = acc[0][mt][nt][r] + o0*m0v[0] + o1*m1v[0] + bi[0];
        float pf = acc[1][mt][nt][r] + o0*m0v[1] + o1*m1v[1] + bi[1];
        float pg = acc[2][mt][nt][r] + o0*m0v[2] + o1*m1v[2] + bi[2];
        float po = acc[3][mt][nt][r] + o0*m0v[3] + o1*m1v[3] + bi[3];
        float cn = sigm(pf)*c_state[off] + sigm(pi)*tanh_f(pg);
        float hn = sigm(po)*tanh_f(cn);
        c_state[off] = cn;
        if (is_final) {
          if (fl) ((float*)out_final)[off] = hn;
          else    ((ushort*)out_final)[off] = f2bf(hn);
        } else {
          ushort hi = f2bf(hn);
          hout_hi[off] = hi;
          hout_lo[off] = f2bf(hn - bf2f(hi));
        }
      }
    }
  }
}

extern "C" void kernel_launch(void* const* d_in, const int* in_sizes, int n_in,
                              void* d_out, int out_size, void* d_ws, size_t ws_size,
                              hipStream_t stream) {
  const void* obs  = d_in[0];
  const void* h0   = d_in[1];
  const void* c0   = d_in[2];
  const void* Wemb = d_in[3];
  const void* bemb = d_in[4];
  const void* Wih  = d_in[5];
  const void* Whh  = d_in[6];
  const void* bih  = d_in[7];
  const void* bhh  = d_in[8];

  char* w = (char*)d_ws;
  int*    flag    = (int*)w;
  float*  M0      = (float*)(w + 256);
  float*  M1      = M0 + G4;
  float*  Beff    = M1 + G4;
  float*  c_state = Beff + G4;                              // 2048*1024 f32 = 8 MB
  ushort* whi     = (ushort*)(c_state + (size_t)B_SZ*HID);  // 8 MB
  ushort* wlo     = whi + (size_t)G4*HID;                   // 8 MB
  ushort* hAhi    = wlo + (size_t)G4*HID;                   // 4 MB
  ushort* hAlo    = hAhi + (size_t)B_SZ*HID;                // 4 MB
  ushort* hBhi    = hAlo + (size_t)B_SZ*HID;                // 4 MB
  ushort* hBlo    = hBhi + (size_t)B_SZ*HID;                // 4 MB
  // total ws use ~40.1 MB

  detect_dtype<<<1, 1, 0, stream>>>((const ushort*)h0, flag);

  long totalCanon = 2L*B_SZ*HID + (long)G4*HID;  // 8,388,608
  canon<<<(int)((totalCanon + 255)/256), 256, 0, stream>>>(
      h0, c0, Whh, flag, hAhi, hAlo, c_state, whi, wlo);

  fold_emb<<<G4, 64, 0, stream>>>(Wih, Wemb, bemb, bih, bhh, flag, M0, M1, Beff);

  dim3 grid(B_SZ / BM, HID / BN);   // 16 x 32 = 512 blocks (2/CU)
  for (int t = 0; t < T_LEN; t++) {
    const ushort* ih = (t & 1) ? hBhi : hAhi;
    const ushort* il = (t & 1) ? hBlo : hAlo;
    ushort* oh = (t & 1) ? hAhi : hBhi;
    ushort* ol = (t & 1) ? hAlo : hBlo;
    lstm_step<<<grid, 256, 0, stream>>>(ih, il, oh, ol, d_out, c_state,
                                        whi, wlo, M0, M1, Beff,
                                        obs, t, flag, (t == T_LEN - 1) ? 1 : 0);
  }
}